// Round 3
// baseline (56303.644 us; speedup 1.0000x reference)
//
#include <hip/hip_runtime.h>
#include <math.h>

#define S 512
#define B 64
#define E 1024
#define H 1024
#define H3 3072
#define MTOT (S * B)
#define KT 32                 // K tiles (K=1024 / 32)
#define CT_T 64               // timesteps per chunk
#define CM (CT_T * B)         // 4096 rows per chunk
#define CFR (CM / 16)         // 256 frag-rows per chunk

typedef __bf16 bf16x8 __attribute__((ext_vector_type(8)));
typedef float f32x4 __attribute__((ext_vector_type(4)));
typedef unsigned short u16x8 __attribute__((ext_vector_type(8)));

// ---------------- workspace layout (float offsets), total ~242 MB ----------------
#define ENC_OFF  0ull
#define ENC_SZ   ((size_t)S * H * B)             // 33,554,432: enc_T [S][H][B]; reused as T [S*B][H] at the end
#define GIC_OFF  (ENC_OFF + ENC_SZ)
#define GIC_SZ   ((size_t)H3 * CM)               // 12,582,912: gi chunk, [3H][CM] col-major
#define ACH_OFF  (GIC_OFF + GIC_SZ)
#define APK_SZ   ((size_t)CFR * KT * 64 * 8 / 2) // 2,097,152 floats (chunk A-pack, u16 count = 2x)
#define ACL_OFF  (ACH_OFF + APK_SZ)
#define WPK_SZ   ((size_t)(H3 / 16) * KT * 64 * 8 / 2)  // 1,572,864 floats
#define WFH_OFF  (ACL_OFF + APK_SZ)
#define WFL_OFF  (WFH_OFF + WPK_SZ)
#define WBH_OFF  (WFL_OFF + WPK_SZ)
#define WBL_OFF  (WBH_OFF + WPK_SZ)
#define WDH_OFF  (WBL_OFF + WPK_SZ)
#define WDL_OFF  (WDH_OFF + WPK_SZ)
#define HA_OFF   (WDL_OFF + WPK_SZ)
#define HB_OFF   (HA_OFF + (size_t)H * B)
#define HFS_OFF  (HB_OFF + (size_t)H * B)
#define HIDA_OFF (HFS_OFF + (size_t)H * B)
#define HIDB_OFF (HIDA_OFF + (size_t)H * B)
#define MT_OFF   (HIDB_OFF + (size_t)H * B)
#define TT_OFF   (MT_OFF + (size_t)H * B)
#define EE_OFF   (TT_OFF + (size_t)H * B)
#define PP_OFF   (EE_OFF + (size_t)B * S)
#define MEM_OFF  (PP_OFF + (size_t)B * S)        // memory [B][3][H]
// END = MEM_OFF + B*3*H = 60,489,728 floats = 241,958,912 bytes

// ---------------- bf16 helpers (RNE) ----------------
__device__ __forceinline__ unsigned short f2bf(float f) {
  unsigned int u = __float_as_uint(f);
  u += 0x7fffu + ((u >> 16) & 1u);
  return (unsigned short)(u >> 16);
}
__device__ __forceinline__ float bf2f(unsigned short h) {
  return __uint_as_float(((unsigned int)h) << 16);
}

// ---------------- tiny utility kernels ----------------
__global__ void kzero(float* p, int n) {
  int i = blockIdx.x * 256 + threadIdx.x;
  if (i < n) p[i] = 0.f;
}
__global__ void kcopy(float* dst, const float* src, int n) {
  int i = blockIdx.x * 256 + threadIdx.x;
  if (i < n) dst[i] = src[i];
}
__global__ void kadd(float* dst, const float* a, const float* b, int n) {
  int i = blockIdx.x * 256 + threadIdx.x;
  if (i < n) dst[i] = a[i] + b[i];
}

// ---------------- split-pack fp32 [R][1024] into hi/lo bf16 MFMA fragments ----------------
// frag f = rt*KT + kt; lane l elem e holds src[rt*16 + (l&15)][kt*32 + (l>>4)*8 + e]
__global__ __launch_bounds__(256) void pack_split(
    const float* __restrict__ src, unsigned short* __restrict__ hi,
    unsigned short* __restrict__ lo) {
  int gid = blockIdx.x * 256 + threadIdx.x;   // one thread per (frag, lane)
  int l = gid & 63;
  int f = gid >> 6;
  int kt = f & (KT - 1);
  int rt = f >> 5;                            // KT == 32
  const float* p = src + (size_t)(rt * 16 + (l & 15)) * 1024 + kt * 32 + (l >> 4) * 8;
  u16x8 h8, l8;
#pragma unroll
  for (int e = 0; e < 8; ++e) {
    float v = p[e];
    unsigned short hb = f2bf(v);
    float r = v - bf2f(hb);
    h8[e] = hb;
    l8[e] = f2bf(r);
  }
  *(u16x8*)(hi + (size_t)gid * 8) = h8;
  *(u16x8*)(lo + (size_t)gid * 8) = l8;
}

// ---------------- MFMA split GEMM: CT[n][m] = sum_k A[m][k]*Bm[n][k] (+bias[n]) ----------------
// A,Bm pre-packed hi/lo fragments (chunk-local frag-row indices). Output TRANSPOSED:
// CT[n * ct_mstride + m]. block = 256 thr = 4 waves (2x2); wave = 64x64; block 128x128.
// grid.x covers Bm frag-rows/8, grid.y covers A frag-rows/8.
__global__ __launch_bounds__(256) void gemm_mfma_split(
    const unsigned short* __restrict__ Ahi, const unsigned short* __restrict__ Alo,
    const unsigned short* __restrict__ Bhi, const unsigned short* __restrict__ Blo,
    const float* __restrict__ bias, float* __restrict__ CT, int ct_mstride) {
  const int tid = threadIdx.x;
  const int l = tid & 63;
  const int w = tid >> 6;
  const int wm = w & 1, wn = w >> 1;
  const int mt0 = blockIdx.y * 8 + wm * 4;
  const int nt0 = blockIdx.x * 8 + wn * 4;

  f32x4 acc[4][4];
#pragma unroll
  for (int i = 0; i < 4; ++i)
#pragma unroll
    for (int j = 0; j < 4; ++j) acc[i][j] = (f32x4)0.f;

  for (int kt = 0; kt < KT; ++kt) {
    bf16x8 ah[4], al[4], bh[4], bl[4];
#pragma unroll
    for (int i = 0; i < 4; ++i) {
      size_t idx = ((size_t)((mt0 + i) * KT + kt) * 64 + l) * 8;
      ah[i] = *(const bf16x8*)(Ahi + idx);
      al[i] = *(const bf16x8*)(Alo + idx);
    }
#pragma unroll
    for (int j = 0; j < 4; ++j) {
      size_t idx = ((size_t)((nt0 + j) * KT + kt) * 64 + l) * 8;
      bh[j] = *(const bf16x8*)(Bhi + idx);
      bl[j] = *(const bf16x8*)(Blo + idx);
    }
#pragma unroll
    for (int i = 0; i < 4; ++i)
#pragma unroll
      for (int j = 0; j < 4; ++j) {
        acc[i][j] = __builtin_amdgcn_mfma_f32_16x16x32_bf16(ah[i], bh[j], acc[i][j], 0, 0, 0);
        acc[i][j] = __builtin_amdgcn_mfma_f32_16x16x32_bf16(ah[i], bl[j], acc[i][j], 0, 0, 0);
        acc[i][j] = __builtin_amdgcn_mfma_f32_16x16x32_bf16(al[i], bh[j], acc[i][j], 0, 0, 0);
      }
  }
  // C/D frag: col(n-dim) = l&15, row(m-dim) = (l>>4)*4 + r
  const int rbase = (l >> 4) * 4;
#pragma unroll
  for (int i = 0; i < 4; ++i) {
    int m0 = (mt0 + i) * 16 + rbase;
#pragma unroll
    for (int j = 0; j < 4; ++j) {
      int n = (nt0 + j) * 16 + (l & 15);
      float bv = bias ? bias[n] : 0.f;
      f32x4 o = acc[i][j];
      o[0] += bv; o[1] += bv; o[2] += bv; o[3] += bv;
      *(f32x4*)(CT + (size_t)n * ct_mstride + m0) = o;
    }
  }
}

// ---------------- per-step GRU kernel (1 j per wave, weight rows read once) ----------------
// gic layout [3H][CM] (chunk-local, tl = t within chunk); h layout hT[k][b].
// mode 0: outp[j*B+b] = hn   mode 1: outp[j*B+b] += hn   mode 2: outp[b*H+j] = hn
__global__ __launch_bounds__(256) void rnn_step(
    const float* __restrict__ gic, int tl, const float* __restrict__ hinT,
    float* __restrict__ houtT, const float* __restrict__ Whh,
    const float* __restrict__ bhh, const float* __restrict__ mask_t,
    float* __restrict__ outp, int mode) {
  __shared__ float hs[64 * 256];  // 64 KB
  const int tid = threadIdx.x;
  const int b = tid & 63;
  const int j = blockIdx.x * 4 + (tid >> 6);   // wave-uniform
  const float* wr = Whh + (size_t)j * H;
  const float* wz = Whh + (size_t)(H + j) * H;
  const float* wn = Whh + (size_t)(2 * H + j) * H;
  float accr = 0.f, accz = 0.f, accn = 0.f;

  for (int kc = 0; kc < H; kc += 256) {
    __syncthreads();
#pragma unroll 8
    for (int i = 0; i < 64; ++i) {
      int idx = i * 256 + tid;
      int k = idx >> 6, bb = idx & 63;
      hs[bb * 256 + ((((k >> 2) ^ (bb & 7)) << 2) | (k & 3))] =
          hinT[(size_t)(kc + k) * B + bb];
    }
    __syncthreads();
#pragma unroll 4
    for (int k4 = 0; k4 < 64; ++k4) {
      int k = kc + k4 * 4;
      float4 h4 = *(const float4*)&hs[b * 256 + ((k4 ^ (b & 7)) << 2)];
      float4 r4 = *(const float4*)(wr + k);
      float4 z4 = *(const float4*)(wz + k);
      float4 n4 = *(const float4*)(wn + k);
      accr += h4.x * r4.x + h4.y * r4.y + h4.z * r4.z + h4.w * r4.w;
      accz += h4.x * z4.x + h4.y * z4.y + h4.z * z4.z + h4.w * z4.w;
      accn += h4.x * n4.x + h4.y * n4.y + h4.z * n4.z + h4.w * n4.w;
    }
  }
  const float* gbase = gic + (size_t)tl * B;
  float gir = gbase[(size_t)j * CM + b];
  float giz = gbase[(size_t)(H + j) * CM + b];
  float gin = gbase[(size_t)(2 * H + j) * CM + b];
  float ghr = accr + bhh[j];
  float ghz = accz + bhh[H + j];
  float ghn = accn + bhh[2 * H + j];
  float r = 1.f / (1.f + expf(-(gir + ghr)));
  float z = 1.f / (1.f + expf(-(giz + ghz)));
  float n = tanhf(gin + r * ghn);
  float hprev = hinT[(size_t)j * B + b];
  float hn = (1.f - z) * n + z * hprev;
  if (mask_t) {
    float m = mask_t[b];
    hn = hn * m + hprev * (1.f - m);
  }
  houtT[(size_t)j * B + b] = hn;
  if (mode == 0) outp[(size_t)j * B + b] = hn;
  else if (mode == 1) outp[(size_t)j * B + b] += hn;
  else outp[(size_t)b * H + j] = hn;
}

// ---------------- memory-loop GRU (x and h both full dot products; runs 3x) ----------------
__global__ __launch_bounds__(256) void memgru_step(
    const float* __restrict__ xT, const float* __restrict__ hinT,
    float* __restrict__ houtT, const float* __restrict__ Wih,
    const float* __restrict__ Whh, const float* __restrict__ bih,
    const float* __restrict__ bhh) {
  __shared__ float xs[16 * 512];
  __shared__ float hsm[16 * 512];
  const int tid = threadIdx.x;
  const int jl = tid & 15, bl = tid >> 4;
  const int j = (blockIdx.x & 63) * 16 + jl;
  const int bbase = (blockIdx.x >> 6) * 16;
  const int b = bbase + bl;
  const float* ir_ = Wih + (size_t)j * E;
  const float* iz_ = Wih + (size_t)(H + j) * E;
  const float* in_ = Wih + (size_t)(2 * H + j) * E;
  const float* hr_ = Whh + (size_t)j * H;
  const float* hz_ = Whh + (size_t)(H + j) * H;
  const float* hn_ = Whh + (size_t)(2 * H + j) * H;
  float air = 0.f, aiz = 0.f, ain = 0.f, ahr = 0.f, ahz = 0.f, ahn = 0.f;
  for (int kc = 0; kc < H; kc += 512) {
    __syncthreads();
#pragma unroll
    for (int i = 0; i < 32; ++i) {
      int idx = i * 256 + tid;
      int k = idx >> 4, bb = idx & 15;
      int sl = bb * 512 + ((((k >> 2) ^ (bb & 3)) << 2) | (k & 3));
      xs[sl] = xT[(size_t)(kc + k) * B + bbase + bb];
      hsm[sl] = hinT[(size_t)(kc + k) * B + bbase + bb];
    }
    __syncthreads();
#pragma unroll 2
    for (int k4 = 0; k4 < 128; ++k4) {
      int k = kc + k4 * 4;
      int sl = bl * 512 + ((k4 ^ (bl & 3)) << 2);
      float4 x4 = *(const float4*)&xs[sl];
      float4 h4 = *(const float4*)&hsm[sl];
      float4 t0 = *(const float4*)(ir_ + k);
      float4 t1 = *(const float4*)(iz_ + k);
      float4 t2 = *(const float4*)(in_ + k);
      air += x4.x * t0.x + x4.y * t0.y + x4.z * t0.z + x4.w * t0.w;
      aiz += x4.x * t1.x + x4.y * t1.y + x4.z * t1.z + x4.w * t1.w;
      ain += x4.x * t2.x + x4.y * t2.y + x4.z * t2.z + x4.w * t2.w;
      t0 = *(const float4*)(hr_ + k);
      t1 = *(const float4*)(hz_ + k);
      t2 = *(const float4*)(hn_ + k);
      ahr += h4.x * t0.x + h4.y * t0.y + h4.z * t0.z + h4.w * t0.w;
      ahz += h4.x * t1.x + h4.y * t1.y + h4.z * t1.z + h4.w * t1.w;
      ahn += h4.x * t2.x + h4.y * t2.y + h4.z * t2.z + h4.w * t2.w;
    }
  }
  float r = 1.f / (1.f + expf(-(air + bih[j] + ahr + bhh[j])));
  float z = 1.f / (1.f + expf(-(aiz + bih[H + j] + ahz + bhh[H + j])));
  float n = tanhf(ain + bih[2 * H + j] + r * (ahn + bhh[2 * H + j]));
  float hprev = hinT[(size_t)j * B + b];
  houtT[(size_t)j * B + b] = (1.f - z) * n + z * hprev;
}

// ---------------- tT[j][b] = sum_k hT[k][b] * W[j][k] ----------------
__global__ __launch_bounds__(256) void gemvT(
    const float* __restrict__ hT, const float* __restrict__ W,
    float* __restrict__ outT) {
  __shared__ float hs[16 * 512];
  const int tid = threadIdx.x;
  const int jl = tid & 15, bl = tid >> 4;
  const int j = (blockIdx.x & 63) * 16 + jl;
  const int bbase = (blockIdx.x >> 6) * 16;
  const int b = bbase + bl;
  const float* wj = W + (size_t)j * H;
  float acc = 0.f;
  for (int kc = 0; kc < H; kc += 512) {
    __syncthreads();
#pragma unroll
    for (int i = 0; i < 32; ++i) {
      int idx = i * 256 + tid;
      int k = idx >> 4, bb = idx & 15;
      hs[bb * 512 + ((((k >> 2) ^ (bb & 3)) << 2) | (k & 3))] =
          hT[(size_t)(kc + k) * B + bbase + bb];
    }
    __syncthreads();
#pragma unroll 4
    for (int k4 = 0; k4 < 128; ++k4) {
      int k = kc + k4 * 4;
      float4 h4 = *(const float4*)&hs[bl * 512 + ((k4 ^ (bl & 3)) << 2)];
      float4 w4 = *(const float4*)(wj + k);
      acc += h4.x * w4.x + h4.y * w4.y + h4.z * w4.z + h4.w * w4.w;
    }
  }
  outT[(size_t)j * B + b] = acc;
}

// ---------------- e[b][tau] = sum_h encT[tau][h][b]*tT[h][b] ----------------
__global__ __launch_bounds__(128) void escore(
    const float* __restrict__ encT, const float* __restrict__ tT,
    float* __restrict__ e) {
  const int b = threadIdx.x & 63;
  const int tau = blockIdx.x * 2 + (threadIdx.x >> 6);
  const float* ep = encT + (size_t)tau * H * B + b;
  float acc = 0.f;
#pragma unroll 4
  for (int h = 0; h < H; ++h) acc += ep[(size_t)h * B] * tT[(size_t)h * B + b];
  e[b * S + tau] = acc;
}

// ---------------- softmax over 512 per b ----------------
__global__ __launch_bounds__(64) void softmax512(
    const float* __restrict__ e, float* __restrict__ p) {
  const int b = blockIdx.x;
  const int lane = threadIdx.x;
  float v[8];
  float mx = -3.4e38f;
#pragma unroll
  for (int i = 0; i < 8; ++i) {
    v[i] = e[b * S + lane + i * 64];
    mx = fmaxf(mx, v[i]);
  }
#pragma unroll
  for (int off = 32; off >= 1; off >>= 1) mx = fmaxf(mx, __shfl_xor(mx, off));
  float sum = 0.f;
#pragma unroll
  for (int i = 0; i < 8; ++i) { v[i] = expf(v[i] - mx); sum += v[i]; }
#pragma unroll
  for (int off = 32; off >= 1; off >>= 1) sum += __shfl_xor(sum, off);
  float inv = 1.f / sum;
#pragma unroll
  for (int i = 0; i < 8; ++i) p[b * S + lane + i * 64] = v[i] * inv;
}

// ---------------- mT[h][b] = sum_tau p[b][tau]*encT[tau][h][b]; also memory[b][slot][h] ----------------
__global__ __launch_bounds__(256) void weight_sum(
    const float* __restrict__ encT, const float* __restrict__ p,
    float* __restrict__ mT, float* __restrict__ memory, int slot) {
  const int b = threadIdx.x & 63;
  const int h = blockIdx.x * 4 + (threadIdx.x >> 6);
  float acc = 0.f;
#pragma unroll 4
  for (int tau = 0; tau < S; ++tau)
    acc += p[b * S + tau] * encT[(size_t)tau * H * B + (size_t)h * B + b];
  mT[(size_t)h * B + b] = acc;
  memory[(size_t)b * 3 * H + (size_t)slot * H + h] = acc;
}

// ---------------- final: out[tb][h] += sum_s softmax_s(mem[b][s]·T[tb]) * mem[b][s][h] ----------------
__global__ __launch_bounds__(256) void final_out(
    const float* __restrict__ T, const float* __restrict__ memory,
    float* __restrict__ out) {
  const int tb = blockIdx.x;
  const int b = tb & 63;
  const int hl = threadIdx.x;
  const float4 t4 = ((const float4*)(T + (size_t)tb * H))[hl];
  const float4 m0 = ((const float4*)(memory + (size_t)b * 3 * H + 0 * H))[hl];
  const float4 m1 = ((const float4*)(memory + (size_t)b * 3 * H + 1 * H))[hl];
  const float4 m2 = ((const float4*)(memory + (size_t)b * 3 * H + 2 * H))[hl];
  float e0 = t4.x * m0.x + t4.y * m0.y + t4.z * m0.z + t4.w * m0.w;
  float e1 = t4.x * m1.x + t4.y * m1.y + t4.z * m1.z + t4.w * m1.w;
  float e2 = t4.x * m2.x + t4.y * m2.y + t4.z * m2.z + t4.w * m2.w;
#pragma unroll
  for (int off = 32; off >= 1; off >>= 1) {
    e0 += __shfl_xor(e0, off);
    e1 += __shfl_xor(e1, off);
    e2 += __shfl_xor(e2, off);
  }
  __shared__ float red[3][4];
  const int w = threadIdx.x >> 6;
  if ((threadIdx.x & 63) == 0) { red[0][w] = e0; red[1][w] = e1; red[2][w] = e2; }
  __syncthreads();
  e0 = red[0][0] + red[0][1] + red[0][2] + red[0][3];
  e1 = red[1][0] + red[1][1] + red[1][2] + red[1][3];
  e2 = red[2][0] + red[2][1] + red[2][2] + red[2][3];
  float mx = fmaxf(e0, fmaxf(e1, e2));
  float x0 = expf(e0 - mx), x1 = expf(e1 - mx), x2 = expf(e2 - mx);
  float inv = 1.f / (x0 + x1 + x2);
  float p0 = x0 * inv, p1 = x1 * inv, p2 = x2 * inv;
  float4 o = ((float4*)(out + (size_t)tb * H))[hl];
  o.x += p0 * m0.x + p1 * m1.x + p2 * m2.x;
  o.y += p0 * m0.y + p1 * m1.y + p2 * m2.y;
  o.z += p0 * m0.z + p1 * m1.z + p2 * m2.z;
  o.w += p0 * m0.w + p1 * m1.w + p2 * m2.w;
  ((float4*)(out + (size_t)tb * H))[hl] = o;
}

// ---------------- host driver ----------------
extern "C" void kernel_launch(void* const* d_in, const int* in_sizes, int n_in,
                              void* d_out, int out_size, void* d_ws, size_t ws_size,
                              hipStream_t stream) {
  const float* emb = (const float*)d_in[0];
  const float* mask = (const float*)d_in[1];
  const float* Wf_ih = (const float*)d_in[2];
  const float* Wf_hh = (const float*)d_in[3];
  const float* bf_ih = (const float*)d_in[4];
  const float* bf_hh = (const float*)d_in[5];
  const float* Wb_ih = (const float*)d_in[6];
  const float* Wb_hh = (const float*)d_in[7];
  const float* bb_ih = (const float*)d_in[8];
  const float* bb_hh = (const float*)d_in[9];
  const float* Wr_ih = (const float*)d_in[10];
  const float* Wr_hh = (const float*)d_in[11];
  const float* br_ih = (const float*)d_in[12];
  const float* br_hh = (const float*)d_in[13];
  const float* Wd_ih = (const float*)d_in[14];
  const float* Wd_hh = (const float*)d_in[15];
  const float* bd_ih = (const float*)d_in[16];
  const float* bd_hh = (const float*)d_in[17];
  const float* W_write = (const float*)d_in[18];
  const float* W_read = (const float*)d_in[19];
  float* out = (float*)d_out;

  float* ws = (float*)d_ws;
  float* enc = ws + ENC_OFF;   // enc during phases; T at the end
  float* gic = ws + GIC_OFF;
  unsigned short* Ah = (unsigned short*)(ws + ACH_OFF);
  unsigned short* Al = (unsigned short*)(ws + ACL_OFF);
  unsigned short* WFh = (unsigned short*)(ws + WFH_OFF);
  unsigned short* WFl = (unsigned short*)(ws + WFL_OFF);
  unsigned short* WBh = (unsigned short*)(ws + WBH_OFF);
  unsigned short* WBl = (unsigned short*)(ws + WBL_OFF);
  unsigned short* WDh = (unsigned short*)(ws + WDH_OFF);
  unsigned short* WDl = (unsigned short*)(ws + WDL_OFF);
  float* hA = ws + HA_OFF;
  float* hB = ws + HB_OFF;
  float* hfs = ws + HFS_OFF;
  float* hidA = ws + HIDA_OFF;
  float* hidB = ws + HIDB_OFF;
  float* mT = ws + MT_OFF;
  float* tT = ws + TT_OFF;
  float* ee = ws + EE_OFF;
  float* pp = ws + PP_OFF;
  float* mem = ws + MEM_OFF;

  const int HBn = H * B;
  dim3 blk256(256), blk128(128), blk64(64);
  dim3 gemm_grid(H3 / 128, CM / 128);   // 24 x 32  (main chunk GEMM)
  dim3 tgemm_grid(CM / 128, H / 128);   // 32 x 8   (T chunk GEMM: A=W_read, B=HN chunk)
  dim3 step_grid(256);
  const int apack_blocks = CFR * KT * 64 / 256;        // 2048
  const int wpack_blocks = (H3 / 16) * KT * 64 / 256;  // 1536
  const int rpack_blocks = (H / 16) * KT * 64 / 256;   // 512

  // ===== pack recurrent-phase input weights once =====
  pack_split<<<wpack_blocks, blk256, 0, stream>>>(Wf_ih, WFh, WFl);
  pack_split<<<wpack_blocks, blk256, 0, stream>>>(Wb_ih, WBh, WBl);
  pack_split<<<wpack_blocks, blk256, 0, stream>>>(Wd_ih, WDh, WDl);

  // ===== encoder forward =====
  kzero<<<HBn / 256, blk256, 0, stream>>>(hA, HBn);
  for (int c = 0; c < S / CT_T; ++c) {
    pack_split<<<apack_blocks, blk256, 0, stream>>>(emb + (size_t)c * CM * E, Ah, Al);
    gemm_mfma_split<<<gemm_grid, blk256, 0, stream>>>(Ah, Al, WFh, WFl, bf_ih, gic, CM);
    for (int tl = 0; tl < CT_T; ++tl) {
      int t = c * CT_T + tl;
      float* hin = (t & 1) ? hB : hA;
      float* hout = (t & 1) ? hA : hB;
      rnn_step<<<step_grid, blk256, 0, stream>>>(gic, tl, hin, hout, Wf_hh, bf_hh,
                                                 mask + t * B, enc + (size_t)t * HBn, 0);
    }
  }
  kcopy<<<HBn / 256, blk256, 0, stream>>>(hfs, hA, HBn);  // 512 steps -> final in hA

  // ===== encoder backward =====
  kzero<<<HBn / 256, blk256, 0, stream>>>(hA, HBn);
  for (int c = S / CT_T - 1; c >= 0; --c) {
    pack_split<<<apack_blocks, blk256, 0, stream>>>(emb + (size_t)c * CM * E, Ah, Al);
    gemm_mfma_split<<<gemm_grid, blk256, 0, stream>>>(Ah, Al, WBh, WBl, bb_ih, gic, CM);
    for (int tl = CT_T - 1; tl >= 0; --tl) {
      int t = c * CT_T + tl;
      int i = S - 1 - t;  // step count parity
      float* hin = (i & 1) ? hB : hA;
      float* hout = (i & 1) ? hA : hB;
      rnn_step<<<step_grid, blk256, 0, stream>>>(gic, tl, hin, hout, Wb_hh, bb_hh,
                                                 mask + t * B, enc + (size_t)t * HBn, 1);
    }
  }
  kadd<<<HBn / 256, blk256, 0, stream>>>(hidA, hfs, hA, HBn);

  // ===== memory loop (3 slots) =====
  kzero<<<HBn / 256, blk256, 0, stream>>>(mT, HBn);
  float* hin = hidA;
  float* hout = hidB;
  for (int s = 0; s < 3; ++s) {
    memgru_step<<<step_grid, blk256, 0, stream>>>(mT, hin, hout, Wr_ih, Wr_hh, br_ih, br_hh);
    gemvT<<<step_grid, blk256, 0, stream>>>(hout, W_write, tT);
    escore<<<dim3(S / 2), blk128, 0, stream>>>(enc, tT, ee);
    softmax512<<<dim3(B), blk64, 0, stream>>>(ee, pp);
    weight_sum<<<dim3(H / 4), blk256, 0, stream>>>(enc, pp, mT, mem, s);
    float* tmp = hin; hin = hout; hout = tmp;
  }

  // ===== decoder =====
  kzero<<<HBn / 256, blk256, 0, stream>>>(hA, HBn);
  for (int c = 0; c < S / CT_T; ++c) {
    pack_split<<<apack_blocks, blk256, 0, stream>>>(emb + (size_t)c * CM * E, Ah, Al);
    gemm_mfma_split<<<gemm_grid, blk256, 0, stream>>>(Ah, Al, WDh, WDl, bd_ih, gic, CM);
    for (int tl = 0; tl < CT_T; ++tl) {
      int t = c * CT_T + tl;
      float* hi = (t & 1) ? hB : hA;
      float* ho = (t & 1) ? hA : hB;
      rnn_step<<<step_grid, blk256, 0, stream>>>(gic, tl, hi, ho, Wd_hh, bd_hh, nullptr,
                                                 out + (size_t)t * B * H, 2);
    }
  }

  // ===== batched decoder attention =====
  // T[tb][h] = sum_k HN[tb][k]*W_read[h][k]. Operand swap: A=W_read-pack, B=HN-chunk-pack;
  // transposed store then emits row-major T. enc region (dead) holds T.
  float* Tbuf = enc;
  pack_split<<<rpack_blocks, blk256, 0, stream>>>(W_read, WFh, WFl);  // reuse dead WF region
  for (int c = 0; c < S / CT_T; ++c) {
    pack_split<<<apack_blocks, blk256, 0, stream>>>(out + (size_t)c * CM * H, Ah, Al);
    gemm_mfma_split<<<tgemm_grid, blk256, 0, stream>>>(WFh, WFl, Ah, Al, nullptr,
                                                       Tbuf + (size_t)c * CM * H, H);
  }
  final_out<<<dim3(S * B), blk256, 0, stream>>>(Tbuf, mem, out);
}